// Round 1
// baseline (184.394 us; speedup 1.0000x reference)
//
#include <hip/hip_runtime.h>
#include <hip/hip_bf16.h>

// Problem constants (match reference)
constexpr int B = 8, T = 64, A = 4, S = 512;
constexpr int V = 32000, EXT_V = 33000;

// Kernel 1: out[b,t,v] = vocab[b,t,v] * coef[b,t] for v<V, 0 for v in [V,EXT_V)
// coef[b,t] = sum_a agent_attn[b,t,a] * gen[b,t,a]
// One block per (b,t) row. float4 vectorized (V%4==0, EXT_V%4==0, rows 16B-aligned).
__global__ void __launch_bounds__(256)
base_kernel(const float* __restrict__ vocab,
            const float* __restrict__ gen,
            const float* __restrict__ agent_attn,
            float* __restrict__ out) {
    const int bt = blockIdx.x;  // 0 .. B*T-1
    float coef = 0.f;
#pragma unroll
    for (int a = 0; a < A; ++a)
        coef += agent_attn[bt * A + a] * gen[bt * A + a];

    const float4* __restrict__ vrow = reinterpret_cast<const float4*>(vocab + (size_t)bt * V);
    float4* __restrict__ orow = reinterpret_cast<float4*>(out + (size_t)bt * EXT_V);
    constexpr int V4 = V / 4;       // 8000
    constexpr int E4 = EXT_V / 4;   // 8250

    for (int i = threadIdx.x; i < E4; i += blockDim.x) {
        float4 r;
        if (i < V4) {
            float4 x = vrow[i];
            r = make_float4(x.x * coef, x.y * coef, x.z * coef, x.w * coef);
        } else {
            r = make_float4(0.f, 0.f, 0.f, 0.f);
        }
        orow[i] = r;
    }
}

// Kernel 2: scatter-add copy probabilities.
// out[b,t,article[b,a,s]] += agent_attn[b,t,a]*(1-gen[b,t,a])*attn[b,t,a,s]
// Block = (b, a, t-chunk of TCH). 512 threads, one per s; article index read once per thread.
constexpr int TCH = 8;  // t values per block
__global__ void __launch_bounds__(512)
scatter_kernel(const float* __restrict__ gen,
               const float* __restrict__ attn,
               const float* __restrict__ agent_attn,
               const int* __restrict__ article,
               float* __restrict__ out) {
    const int nchunk = T / TCH;             // 8
    const int blk = blockIdx.x;             // 0 .. B*A*nchunk-1
    const int tc = blk % nchunk;
    const int ba = blk / nchunk;
    const int b = ba / A;
    const int a = ba % A;
    const int s = threadIdx.x;              // 0..511

    const int idx = article[(b * A + a) * S + s];

#pragma unroll
    for (int tt = 0; tt < TCH; ++tt) {
        const int t = tc * TCH + tt;
        const int bta = (b * T + t) * A + a;
        const float g = gen[bta];
        const float w = agent_attn[bta] * (1.0f - g);
        const float val = w * attn[(size_t)bta * S + s];
        atomicAdd(out + (size_t)(b * T + t) * EXT_V + idx, val);
    }
}

extern "C" void kernel_launch(void* const* d_in, const int* in_sizes, int n_in,
                              void* d_out, int out_size, void* d_ws, size_t ws_size,
                              hipStream_t stream) {
    const float* vocab      = (const float*)d_in[0];  // [B,T,V]
    const float* gen        = (const float*)d_in[1];  // [B,T,A]
    const float* attn       = (const float*)d_in[2];  // [B,T,A,S]
    const float* agent_attn = (const float*)d_in[3];  // [B,T,A]
    const int*   article    = (const int*)d_in[4];    // [B,A,S]
    float* out = (float*)d_out;                       // [B,T,EXT_V]

    base_kernel<<<B * T, 256, 0, stream>>>(vocab, gen, agent_attn, out);
    scatter_kernel<<<B * A * (T / TCH), 512, 0, stream>>>(gen, attn, agent_attn, article, out);
}

// Round 2
// 128.271 us; speedup vs baseline: 1.4375x; 1.4375x over previous
//
#include <hip/hip_runtime.h>
#include <hip/hip_bf16.h>

// Problem constants (match reference)
constexpr int B = 8, T = 64, A = 4, S = 512;
constexpr int V = 32000, EXT_V = 33000;
constexpr int V4 = V / 4;       // 8000
constexpr int E4 = EXT_V / 4;   // 8250
constexpr int NTHREADS = 1024;

// Fully fused: one block per (b,t) row.
//   out[b,t,v] = coef[b,t]*vocab[b,t,v]  (v<V)
//              + sum over (a,s) with article[b,a,s]==v of
//                agent_attn[b,t,a]*(1-gen[b,t,a])*attn[b,t,a,s]
// The scatter is privatized into a 129 KB LDS row (EXT_V floats), added with
// LDS atomics (2048 per block), then a single fused float4 streaming pass
// writes the output. No global atomics, single read of vocab, single write of out.
__global__ void __launch_bounds__(NTHREADS, 1)
fused_kernel(const float* __restrict__ vocab,
             const float* __restrict__ gen,
             const float* __restrict__ attn,
             const float* __restrict__ agent_attn,
             const int* __restrict__ article,
             float* __restrict__ out) {
    __shared__ float smem[EXT_V];  // 132000 B of the 160 KiB LDS
    const int bt = blockIdx.x;     // 0 .. B*T-1
    const int b = bt / T;
    const int tid = threadIdx.x;

    // 1) zero the LDS row (float4, 8250/1024 ~ 8.06 iters)
    float4* s4 = reinterpret_cast<float4*>(smem);
    for (int i = tid; i < E4; i += NTHREADS)
        s4[i] = make_float4(0.f, 0.f, 0.f, 0.f);

    // 2) coef = sum_a agent_attn*gen (scalar loads, L1/L2-hot: 8 floats)
    float coef = 0.f;
#pragma unroll
    for (int a = 0; a < A; ++a)
        coef += agent_attn[bt * A + a] * gen[bt * A + a];

    __syncthreads();

    // 3) scatter A*S = 2048 contributions into LDS (2 per thread)
#pragma unroll
    for (int k = 0; k < (A * S) / NTHREADS; ++k) {
        const int j = tid + k * NTHREADS;
        const int a = j >> 9;        // j / S
        const int s = j & (S - 1);   // j % S
        const int bta = bt * A + a;
        const float g = gen[bta];
        const float w = agent_attn[bta] * (1.0f - g);
        const int idx = article[(b * A + a) * S + s];
        const float val = w * attn[(size_t)bta * S + s];
        atomicAdd(smem + idx, val);
    }
    __syncthreads();

    // 4) fused streaming pass: out = vocab*coef + lds  (zeros beyond V)
    const float4* __restrict__ vrow = reinterpret_cast<const float4*>(vocab + (size_t)bt * V);
    float4* __restrict__ orow = reinterpret_cast<float4*>(out + (size_t)bt * EXT_V);
    for (int i = tid; i < E4; i += NTHREADS) {
        float4 r = s4[i];
        if (i < V4) {
            const float4 x = vrow[i];
            r.x += x.x * coef;
            r.y += x.y * coef;
            r.z += x.z * coef;
            r.w += x.w * coef;
        }
        orow[i] = r;
    }
}

extern "C" void kernel_launch(void* const* d_in, const int* in_sizes, int n_in,
                              void* d_out, int out_size, void* d_ws, size_t ws_size,
                              hipStream_t stream) {
    const float* vocab      = (const float*)d_in[0];  // [B,T,V]
    const float* gen        = (const float*)d_in[1];  // [B,T,A]
    const float* attn       = (const float*)d_in[2];  // [B,T,A,S]
    const float* agent_attn = (const float*)d_in[3];  // [B,T,A]
    const int*   article    = (const int*)d_in[4];    // [B,A,S]
    float* out = (float*)d_out;                       // [B,T,EXT_V]

    fused_kernel<<<B * T, NTHREADS, 0, stream>>>(vocab, gen, attn, agent_attn, article, out);
}

// Round 3
// 124.583 us; speedup vs baseline: 1.4801x; 1.0296x over previous
//
#include <hip/hip_runtime.h>
#include <hip/hip_bf16.h>

// Problem constants (match reference)
constexpr int B = 8, T = 64, A = 4, S = 512;
constexpr int V = 32000, EXT_V = 33000;
constexpr int V4 = V / 4;            // 8000
constexpr int HALF = EXT_V / 2;      // 16500 floats (divisible by 4)
constexpr int H4 = HALF / 4;         // 4125 float4s per half
constexpr int NTHREADS = 1024;

// Fused, half-row-split: 2 blocks per (b,t) row, each owning a 16500-wide
// vocab range privatized in 66 KB LDS -> 2 blocks/CU, 32 waves/CU.
//   out[b,t,v] = coef[b,t]*vocab[b,t,v] (v<V)
//              + sum_{(a,s): article[b,a,s]==v} agent_attn*(1-gen)*attn
// Each block scans all A*S=2048 (a,s) pairs and keeps those whose index
// falls in its half-range (LDS atomics), then streams its half fused with
// the vocab scale. No global atomics; out written exactly once.
__global__ void __launch_bounds__(NTHREADS, 2)
fused_kernel(const float* __restrict__ vocab,
             const float* __restrict__ gen,
             const float* __restrict__ attn,
             const float* __restrict__ agent_attn,
             const int* __restrict__ article,
             float* __restrict__ out) {
    __shared__ float smem[HALF];     // 66 000 B
    const int blk = blockIdx.x;      // 0 .. 2*B*T-1
    const int bt = blk >> 1;
    const int half = blk & 1;
    const int vbase = half * HALF;
    const int b = bt / T;
    const int tid = threadIdx.x;

    // 1) zero LDS half (float4)
    float4* s4 = reinterpret_cast<float4*>(smem);
    for (int i = tid; i < H4; i += NTHREADS)
        s4[i] = make_float4(0.f, 0.f, 0.f, 0.f);

    // 2) coef = sum_a agent_attn*gen (8 scalar loads, L2-hot)
    float coef = 0.f;
#pragma unroll
    for (int a = 0; a < A; ++a)
        coef += agent_attn[bt * A + a] * gen[bt * A + a];

    __syncthreads();

    // 3) scan all 2048 (a,s) pairs; scatter those in [vbase, vbase+HALF)
#pragma unroll
    for (int k = 0; k < (A * S) / NTHREADS; ++k) {
        const int j = tid + k * NTHREADS;
        const int a = j >> 9;        // j / S
        const int s = j & (S - 1);   // j % S
        const int bta = bt * A + a;
        const int idx = article[(b * A + a) * S + s] - vbase;
        if ((unsigned)idx < (unsigned)HALF) {
            const float g = gen[bta];
            const float w = agent_attn[bta] * (1.0f - g);
            const float val = w * attn[(size_t)bta * S + s];
            atomicAdd(smem + idx, val);
        }
    }
    __syncthreads();

    // 4) fused streaming pass over this half: out = vocab*coef + lds
    const float4* __restrict__ vrow = reinterpret_cast<const float4*>(vocab + (size_t)bt * V);
    float4* __restrict__ orow = reinterpret_cast<float4*>(out + (size_t)bt * EXT_V);
    const int g4base = vbase / 4;
    for (int i = tid; i < H4; i += NTHREADS) {
        const int gi = g4base + i;
        float4 r = s4[i];
        if (gi < V4) {
            const float4 x = vrow[gi];
            r.x += x.x * coef;
            r.y += x.y * coef;
            r.z += x.z * coef;
            r.w += x.w * coef;
        }
        orow[gi] = r;
    }
}

extern "C" void kernel_launch(void* const* d_in, const int* in_sizes, int n_in,
                              void* d_out, int out_size, void* d_ws, size_t ws_size,
                              hipStream_t stream) {
    const float* vocab      = (const float*)d_in[0];  // [B,T,V]
    const float* gen        = (const float*)d_in[1];  // [B,T,A]
    const float* attn       = (const float*)d_in[2];  // [B,T,A,S]
    const float* agent_attn = (const float*)d_in[3];  // [B,T,A]
    const int*   article    = (const int*)d_in[4];    // [B,A,S]
    float* out = (float*)d_out;                       // [B,T,EXT_V]

    fused_kernel<<<2 * B * T, NTHREADS, 0, stream>>>(vocab, gen, attn, agent_attn, article, out);
}

// Round 8
// 123.039 us; speedup vs baseline: 1.4987x; 1.0125x over previous
//
#include <hip/hip_runtime.h>
#include <hip/hip_bf16.h>

// Problem constants (match reference)
constexpr int B = 8, T = 64, A = 4, S = 512;
constexpr int V = 32000, EXT_V = 33000;
constexpr int V4 = V / 4;            // 8000 float4s of vocab per row
constexpr int HALF = EXT_V / 2;      // 16500 floats (divisible by 4)
constexpr int H4 = HALF / 4;         // 4125 float4s per half
constexpr int NTHREADS = 1024;
constexpr int NBLK = 2 * B * T;      // 1024 blocks (divisible by 8 XCDs)

// Fused, half-row-split, latency-restructured:
//   - 2 blocks per (b,t) row, each privatizing a 66 KB LDS half-range
//   - scatter inputs + first vocab chunks prefetched to registers BEFORE the
//     LDS zero phase (global-load latency hides under zeroing + barrier)
//   - XCD-chunked blockIdx swizzle: both halves of a bt (sharing attn/article)
//     and neighboring bt's land on the same XCD's L2
__global__ void __launch_bounds__(NTHREADS, 2)
fused_kernel(const float* __restrict__ vocab,
             const float* __restrict__ gen,
             const float* __restrict__ attn,
             const float* __restrict__ agent_attn,
             const int* __restrict__ article,
             float* __restrict__ out) {
    __shared__ float smem[HALF];     // 66 000 B -> 2 blocks/CU
    // bijective XCD-chunk swizzle: XCD x gets logical blocks [x*128,(x+1)*128)
    constexpr int PER_XCD = NBLK / 8;          // 128
    const int l = (blockIdx.x & 7) * PER_XCD + (blockIdx.x >> 3);
    const int bt = l >> 1;
    const int half = l & 1;
    const int vbase = half * HALF;
    const int b = bt / T;
    const int tid = threadIdx.x;

    // ---- Phase A: issue ALL latency-critical global loads into registers ----
    // scatter pair 0: j0 = tid, pair 1: j1 = tid + 1024  (A*S = 2048 total)
    const int a0 = tid >> 9, s0 = tid & (S - 1);
    const int j1 = tid + NTHREADS;
    const int a1 = j1 >> 9, s1 = j1 & (S - 1);
    const int bta0 = bt * A + a0, bta1 = bt * A + a1;
    const int idx0 = article[(b * A + a0) * S + s0] - vbase;
    const int idx1 = article[(b * A + a1) * S + s1] - vbase;
    const float av0 = attn[(size_t)bta0 * S + s0];
    const float av1 = attn[(size_t)bta1 * S + s1];
    const float w0 = agent_attn[bta0] * (1.0f - gen[bta0]);
    const float w1 = agent_attn[bta1] * (1.0f - gen[bta1]);

    float coef = 0.f;
#pragma unroll
    for (int a = 0; a < A; ++a)
        coef += agent_attn[bt * A + a] * gen[bt * A + a];

    // vocab prefetch for stream iterations k=0,1
    const float4* __restrict__ vrow = reinterpret_cast<const float4*>(vocab + (size_t)bt * V);
    const int g4base = vbase / 4;
    const int gi0 = g4base + tid;
    const int gi1 = g4base + tid + NTHREADS;
    const bool h0 = gi0 < V4;
    const bool h1 = gi1 < V4;
    float4 p0 = h0 ? vrow[gi0] : make_float4(0.f, 0.f, 0.f, 0.f);
    float4 p1 = h1 ? vrow[gi1] : make_float4(0.f, 0.f, 0.f, 0.f);

    // ---- Phase B: zero the LDS half (overlaps with in-flight loads above) ----
    float4* s4 = reinterpret_cast<float4*>(smem);
    for (int i = tid; i < H4; i += NTHREADS)
        s4[i] = make_float4(0.f, 0.f, 0.f, 0.f);
    __syncthreads();

    // ---- Phase C: LDS scatter from registers (no global loads here) ----
    if ((unsigned)idx0 < (unsigned)HALF) atomicAdd(smem + idx0, w0 * av0);
    if ((unsigned)idx1 < (unsigned)HALF) atomicAdd(smem + idx1, w1 * av1);
    __syncthreads();

    // ---- Phase D: fused stream: out = vocab*coef + lds ----
    float4* __restrict__ orow = reinterpret_cast<float4*>(out + (size_t)bt * EXT_V);
    {   // k = 0 (prefetched)
        float4 r = s4[tid];
        r.x += p0.x * coef; r.y += p0.y * coef; r.z += p0.z * coef; r.w += p0.w * coef;
        orow[gi0] = r;
    }
    {   // k = 1 (prefetched)
        float4 r = s4[tid + NTHREADS];
        r.x += p1.x * coef; r.y += p1.y * coef; r.z += p1.z * coef; r.w += p1.w * coef;
        orow[gi1] = r;
    }
    for (int i = tid + 2 * NTHREADS; i < H4; i += NTHREADS) {
        const int gi = g4base + i;
        float4 r = s4[i];
        if (gi < V4) {
            const float4 x = vrow[gi];
            r.x += x.x * coef; r.y += x.y * coef; r.z += x.z * coef; r.w += x.w * coef;
        }
        orow[gi] = r;
    }
}

extern "C" void kernel_launch(void* const* d_in, const int* in_sizes, int n_in,
                              void* d_out, int out_size, void* d_ws, size_t ws_size,
                              hipStream_t stream) {
    const float* vocab      = (const float*)d_in[0];  // [B,T,V]
    const float* gen        = (const float*)d_in[1];  // [B,T,A]
    const float* attn       = (const float*)d_in[2];  // [B,T,A,S]
    const float* agent_attn = (const float*)d_in[3];  // [B,T,A]
    const int*   article    = (const int*)d_in[4];    // [B,A,S]
    float* out = (float*)d_out;                       // [B,T,EXT_V]

    fused_kernel<<<NBLK, NTHREADS, 0, stream>>>(vocab, gen, attn, agent_attn, article, out);
}

// Round 9
// 121.640 us; speedup vs baseline: 1.5159x; 1.0115x over previous
//
#include <hip/hip_runtime.h>
#include <hip/hip_bf16.h>

// Problem constants (match reference)
constexpr int B = 8, T = 64, A = 4, S = 512;
constexpr int V = 32000, EXT_V = 33000;
constexpr int V4 = V / 4;           // 8000 float4s of vocab per row
constexpr int QLEN = 8256;          // floats per quarter q=0..2 (q=3: 8232); /4 aligned
constexpr int Q4 = QLEN / 4;        // 2064 float4s
constexpr int NTH = 512;
constexpr int NBLK = 4 * B * T;     // 2048 blocks (divisible by 8 XCDs)

// Fused scatter+scale, quarter-row split:
//   - 4 blocks per (b,t) row, each privatizing a 33 KB LDS quarter-range
//     -> 4 blocks/CU x 8 waves = 32 waves/CU, finer barriers, more overlap
//   - ALL global reads (scatter inputs + the thread's whole vocab slice)
//     issued in Phase A; stream phase is pure LDS-read+FMA+store
//   - XCD-chunked swizzle: one b per XCD; 4 quarters of a bt adjacent
__global__ void __launch_bounds__(NTH, 8)
fused_kernel(const float* __restrict__ vocab,
             const float* __restrict__ gen,
             const float* __restrict__ attn,
             const float* __restrict__ agent_attn,
             const int* __restrict__ article,
             float* __restrict__ out) {
    __shared__ float smem[QLEN];    // 33 024 B -> 4 blocks/CU
    constexpr int PER_XCD = NBLK / 8;          // 256
    const int l = (blockIdx.x & 7) * PER_XCD + (blockIdx.x >> 3);  // bijective
    const int bt = l >> 2;
    const int q  = l & 3;
    const int vbase = q * QLEN;
    const int vlen  = (q == 3) ? (EXT_V - 3 * QLEN) : QLEN;   // 8232 : 8256
    const int vlen4 = vlen >> 2;                              // 2058 : 2064
    const int b = bt / T;
    const int tid = threadIdx.x;

    // ---- Phase A: issue ALL global reads ----
    // scatter pair k has a=k, s=tid (since S == NTH == 512): coalesced
    int   sidx[4];
    float sval[4];
#pragma unroll
    for (int k = 0; k < A; ++k) {
        sidx[k] = article[(b * A + k) * S + tid] - vbase;
        sval[k] = attn[(size_t)(bt * A + k) * S + tid];
    }
    float coef = 0.f;
    float wA[4];
#pragma unroll
    for (int k = 0; k < A; ++k) {
        const float g  = gen[bt * A + k];
        const float aa = agent_attn[bt * A + k];
        coef += aa * g;
        wA[k] = aa * (1.0f - g);
    }
#pragma unroll
    for (int k = 0; k < A; ++k) sval[k] *= wA[k];

    // vocab prefetch: the thread's entire quarter slice (4 float4 + remainder)
    const float4* __restrict__ vrow = reinterpret_cast<const float4*>(vocab + (size_t)bt * V);
    const int g4base = vbase >> 2;
    float4 p[4];
#pragma unroll
    for (int k = 0; k < 4; ++k) {
        const int gi = g4base + tid + k * NTH;
        p[k] = (gi < V4) ? vrow[gi] : make_float4(0.f, 0.f, 0.f, 0.f);
    }
    const int irem = 4 * NTH + tid;            // 2048 + tid
    const bool has_rem = irem < vlen4;         // 16 threads (q<3) / 10 (q=3)
    float4 prem = make_float4(0.f, 0.f, 0.f, 0.f);
    if (has_rem && (g4base + irem) < V4) prem = vrow[g4base + irem];

    // ---- Phase B: zero the LDS quarter (loads above still in flight) ----
    float4* s4 = reinterpret_cast<float4*>(smem);
#pragma unroll
    for (int k = 0; k < 4; ++k)
        s4[tid + k * NTH] = make_float4(0.f, 0.f, 0.f, 0.f);
    if (tid < Q4 - 4 * NTH)                    // last 16 float4s
        s4[4 * NTH + tid] = make_float4(0.f, 0.f, 0.f, 0.f);
    __syncthreads();

    // ---- Phase C: LDS scatter from registers ----
#pragma unroll
    for (int k = 0; k < A; ++k)
        if ((unsigned)sidx[k] < (unsigned)vlen)
            atomicAdd(smem + sidx[k], sval[k]);
    __syncthreads();

    // ---- Phase D: pure stream: out = prefetched vocab*coef + lds ----
    float4* __restrict__ orow = reinterpret_cast<float4*>(out + (size_t)bt * EXT_V);
#pragma unroll
    for (int k = 0; k < 4; ++k) {
        const int i = tid + k * NTH;
        float4 r = s4[i];
        r.x += p[k].x * coef; r.y += p[k].y * coef;
        r.z += p[k].z * coef; r.w += p[k].w * coef;
        orow[g4base + i] = r;
    }
    if (has_rem) {
        float4 r = s4[irem];
        r.x += prem.x * coef; r.y += prem.y * coef;
        r.z += prem.z * coef; r.w += prem.w * coef;
        orow[g4base + irem] = r;
    }
}

extern "C" void kernel_launch(void* const* d_in, const int* in_sizes, int n_in,
                              void* d_out, int out_size, void* d_ws, size_t ws_size,
                              hipStream_t stream) {
    const float* vocab      = (const float*)d_in[0];  // [B,T,V]
    const float* gen        = (const float*)d_in[1];  // [B,T,A]
    const float* attn       = (const float*)d_in[2];  // [B,T,A,S]
    const float* agent_attn = (const float*)d_in[3];  // [B,T,A]
    const int*   article    = (const int*)d_in[4];    // [B,A,S]
    float* out = (float*)d_out;                       // [B,T,EXT_V]

    fused_kernel<<<NBLK, NTH, 0, stream>>>(vocab, gen, attn, agent_attn, article, out);
}